// Round 1
// baseline (20367.128 us; speedup 1.0000x reference)
//
#include <hip/hip_runtime.h>
#include <cstddef>

#define NN 883
#define BB 64
#define TT 12
#define EMB 10

// ---------------- adjacency: A = softmax(relu(E E^T), axis=1) ----------------
__global__ __launch_bounds__(256) void adj_kernel(const float* __restrict__ E,
                                                  float* __restrict__ A) {
  const int n = blockIdx.x;
  const int tid = threadIdx.x;
  __shared__ float sE[EMB];
  __shared__ float sred[256];
  if (tid < EMB) sE[tid] = E[n * EMB + tid];
  __syncthreads();
  float lmax = 0.0f;
  for (int m = tid; m < NN; m += 256) {
    float d = 0.0f;
#pragma unroll
    for (int e = 0; e < EMB; ++e) d += sE[e] * E[m * EMB + e];
    d = fmaxf(d, 0.0f);
    A[(size_t)n * NN + m] = d;
    lmax = fmaxf(lmax, d);
  }
  sred[tid] = lmax;
  __syncthreads();
  for (int s = 128; s > 0; s >>= 1) {
    if (tid < s) sred[tid] = fmaxf(sred[tid], sred[tid + s]);
    __syncthreads();
  }
  const float mx = sred[0];
  __syncthreads();
  float lsum = 0.0f;
  for (int m = tid; m < NN; m += 256) {
    float v = expf(A[(size_t)n * NN + m] - mx);
    A[(size_t)n * NN + m] = v;
    lsum += v;
  }
  sred[tid] = lsum;
  __syncthreads();
  for (int s = 128; s > 0; s >>= 1) {
    if (tid < s) sred[tid] += sred[tid + s];
    __syncthreads();
  }
  const float inv = 1.0f / sred[0];
  for (int m = tid; m < NN; m += 256) A[(size_t)n * NN + m] *= inv;
}

// ---------------- tiled fp32 GEMM: Y[NN x L] = A[NN x NN] * X[NN x L] --------
__global__ __launch_bounds__(256) void gemm_kernel(const float* __restrict__ Am,
                                                   const float* __restrict__ X,
                                                   float* __restrict__ Y, int L) {
  const int bm = blockIdx.y * 64;
  const int bl = blockIdx.x * 64;
  const int tid = threadIdx.x;
  __shared__ float As[16][65];
  __shared__ float Xs[16][65];
  const int tx = tid & 15, ty = tid >> 4;
  float acc[4][4] = {};
  for (int k0 = 0; k0 < NN; k0 += 16) {
    for (int i = tid; i < 64 * 16; i += 256) {
      int r = i >> 4, c = i & 15;
      int gm = bm + r, gk = k0 + c;
      As[c][r] = (gm < NN && gk < NN) ? Am[(size_t)gm * NN + gk] : 0.0f;
    }
    for (int i = tid; i < 16 * 64; i += 256) {
      int r = i >> 6, c = i & 63;
      int gk = k0 + r, gl = bl + c;
      Xs[r][c] = (gk < NN && gl < L) ? X[(size_t)gk * L + gl] : 0.0f;
    }
    __syncthreads();
#pragma unroll
    for (int kk = 0; kk < 16; ++kk) {
      float av[4], xv[4];
#pragma unroll
      for (int i2 = 0; i2 < 4; ++i2) av[i2] = As[kk][ty * 4 + i2];
#pragma unroll
      for (int j = 0; j < 4; ++j) xv[j] = Xs[kk][tx * 4 + j];
#pragma unroll
      for (int i2 = 0; i2 < 4; ++i2)
#pragma unroll
        for (int j = 0; j < 4; ++j) acc[i2][j] += av[i2] * xv[j];
    }
    __syncthreads();
  }
#pragma unroll
  for (int i2 = 0; i2 < 4; ++i2) {
    int gm = bm + ty * 4 + i2;
    if (gm >= NN) continue;
#pragma unroll
    for (int j = 0; j < 4; ++j) {
      int gl = bl + tx * 4 + j;
      if (gl < L) Y[(size_t)gm * L + gl] = acc[i2][j];
    }
  }
}

// ---------------- concat builders (node-major [n][b][c] layout) --------------
__global__ __launch_bounds__(256) void concat_l0_a(const float* __restrict__ src,
                                                   const float* __restrict__ h0,
                                                   float* __restrict__ XH, int t) {
  int i = blockIdx.x * 256 + threadIdx.x;
  if (i >= NN * BB * 65) return;
  int c = i % 65;
  int nb = i / 65;
  int b = nb & 63;
  int n = nb >> 6;
  XH[i] = (c == 0) ? src[((size_t)b * TT + t) * NN + n]
                   : h0[(size_t)nb * 64 + (c - 1)];
}

__global__ __launch_bounds__(256) void concat_l0_b(const float* __restrict__ src,
                                                   const float* __restrict__ h0,
                                                   const float* __restrict__ ZR,
                                                   float* __restrict__ XH, int t) {
  int i = blockIdx.x * 256 + threadIdx.x;
  if (i >= NN * BB * 65) return;
  int c = i % 65;
  int nb = i / 65;
  int b = nb & 63;
  int n = nb >> 6;
  XH[i] = (c == 0) ? src[((size_t)b * TT + t) * NN + n]
                   : ZR[(size_t)nb * 128 + (c - 1)] * h0[(size_t)nb * 64 + (c - 1)];
}

__global__ __launch_bounds__(256) void concat_l1_a(const float* __restrict__ h0,
                                                   const float* __restrict__ h1,
                                                   float* __restrict__ XH) {
  int i = blockIdx.x * 256 + threadIdx.x;
  if (i >= NN * BB * 128) return;
  int c = i & 127;
  int nb = i >> 7;
  XH[i] = (c < 64) ? h0[(size_t)nb * 64 + c] : h1[(size_t)nb * 64 + (c - 64)];
}

__global__ __launch_bounds__(256) void concat_l1_b(const float* __restrict__ h0,
                                                   const float* __restrict__ h1,
                                                   const float* __restrict__ ZR,
                                                   float* __restrict__ XH) {
  int i = blockIdx.x * 256 + threadIdx.x;
  if (i >= NN * BB * 128) return;
  int c = i & 127;
  int nb = i >> 7;
  XH[i] = (c < 64) ? h0[(size_t)nb * 64 + c]
                   : ZR[(size_t)nb * 128 + (c - 64)] * h1[(size_t)nb * 64 + (c - 64)];
}

// ---------------- fused node-specific gate gconv + sigmoid -------------------
// One block per node n. W[n] = sum_d E[n,d]*wpool[d] generated in LDS.
template <int CIN>
__global__ __launch_bounds__(256) void gate_kernel(const float* __restrict__ XH,
                                                   const float* __restrict__ G,
                                                   const float* __restrict__ E,
                                                   const float* __restrict__ wpool,
                                                   const float* __restrict__ bpool,
                                                   float* __restrict__ ZR) {
  constexpr int CIN_P = (CIN & 1) ? CIN + 2 : CIN + 3;  // bank-conflict pad
  const int n = blockIdx.x;
  const int tid = threadIdx.x;
  __shared__ float sE[EMB];
  __shared__ float sXH[64 * CIN_P];
  __shared__ float sG[64 * CIN_P];
  __shared__ float sW[2 * CIN * 64];
  __shared__ float sB[64];
  if (tid < EMB) sE[tid] = E[n * EMB + tid];
  for (int i = tid; i < 64 * CIN; i += 256) {
    int b = i / CIN, c = i - b * CIN;
    sXH[b * CIN_P + c] = XH[(size_t)n * 64 * CIN + i];
    sG[b * CIN_P + c] = G[(size_t)n * 64 * CIN + i];
  }
  __syncthreads();
  const int tx = tid & 15, ty = tid >> 4;
  for (int och = 0; och < 128; och += 64) {
    for (int i = tid; i < 2 * CIN * 64; i += 256) {
      int ki = i >> 6, oo = i & 63;
      int k = (ki >= CIN) ? 1 : 0;
      int ii = ki - k * CIN;
      float w = 0.0f;
#pragma unroll
      for (int d = 0; d < EMB; ++d)
        w += sE[d] * wpool[(((size_t)d * 2 + k) * CIN + ii) * 128 + och + oo];
      sW[ki * 64 + oo] = w;
    }
    if (tid < 64) {
      float bb = 0.0f;
#pragma unroll
      for (int d = 0; d < EMB; ++d) bb += sE[d] * bpool[d * 128 + och + tid];
      sB[tid] = bb;
    }
    __syncthreads();
    float acc[4][4] = {};
    for (int ii = 0; ii < CIN; ++ii) {
      float xa[4], ga[4], wa[4], wg[4];
#pragma unroll
      for (int i2 = 0; i2 < 4; ++i2) {
        xa[i2] = sXH[(ty * 4 + i2) * CIN_P + ii];
        ga[i2] = sG[(ty * 4 + i2) * CIN_P + ii];
      }
#pragma unroll
      for (int j = 0; j < 4; ++j) {
        wa[j] = sW[ii * 64 + tx * 4 + j];
        wg[j] = sW[(CIN + ii) * 64 + tx * 4 + j];
      }
#pragma unroll
      for (int i2 = 0; i2 < 4; ++i2)
#pragma unroll
        for (int j = 0; j < 4; ++j) acc[i2][j] += xa[i2] * wa[j] + ga[i2] * wg[j];
    }
#pragma unroll
    for (int i2 = 0; i2 < 4; ++i2) {
      int b = ty * 4 + i2;
#pragma unroll
      for (int j = 0; j < 4; ++j) {
        int o = och + tx * 4 + j;
        float v = acc[i2][j] + sB[tx * 4 + j];
        ZR[((size_t)n * 64 + b) * 128 + o] = 1.0f / (1.0f + expf(-v));
      }
    }
    __syncthreads();
  }
}

// ---------------- fused node-specific cand gconv + tanh + GRU update ---------
template <int CIN>
__global__ __launch_bounds__(256) void cand_kernel(const float* __restrict__ XH,
                                                   const float* __restrict__ G,
                                                   const float* __restrict__ E,
                                                   const float* __restrict__ wpool,
                                                   const float* __restrict__ bpool,
                                                   const float* __restrict__ ZR,
                                                   float* __restrict__ h) {
  constexpr int CIN_P = (CIN & 1) ? CIN + 2 : CIN + 3;
  const int n = blockIdx.x;
  const int tid = threadIdx.x;
  __shared__ float sE[EMB];
  __shared__ float sXH[64 * CIN_P];
  __shared__ float sG[64 * CIN_P];
  __shared__ float sW[2 * CIN * 64];
  __shared__ float sB[64];
  if (tid < EMB) sE[tid] = E[n * EMB + tid];
  for (int i = tid; i < 64 * CIN; i += 256) {
    int b = i / CIN, c = i - b * CIN;
    sXH[b * CIN_P + c] = XH[(size_t)n * 64 * CIN + i];
    sG[b * CIN_P + c] = G[(size_t)n * 64 * CIN + i];
  }
  __syncthreads();
  for (int i = tid; i < 2 * CIN * 64; i += 256) {
    int ki = i >> 6, oo = i & 63;
    int k = (ki >= CIN) ? 1 : 0;
    int ii = ki - k * CIN;
    float w = 0.0f;
#pragma unroll
    for (int d = 0; d < EMB; ++d)
      w += sE[d] * wpool[(((size_t)d * 2 + k) * CIN + ii) * 64 + oo];
    sW[ki * 64 + oo] = w;
  }
  if (tid < 64) {
    float bb = 0.0f;
#pragma unroll
    for (int d = 0; d < EMB; ++d) bb += sE[d] * bpool[d * 64 + tid];
    sB[tid] = bb;
  }
  __syncthreads();
  const int tx = tid & 15, ty = tid >> 4;
  float acc[4][4] = {};
  for (int ii = 0; ii < CIN; ++ii) {
    float xa[4], ga[4], wa[4], wg[4];
#pragma unroll
    for (int i2 = 0; i2 < 4; ++i2) {
      xa[i2] = sXH[(ty * 4 + i2) * CIN_P + ii];
      ga[i2] = sG[(ty * 4 + i2) * CIN_P + ii];
    }
#pragma unroll
    for (int j = 0; j < 4; ++j) {
      wa[j] = sW[ii * 64 + tx * 4 + j];
      wg[j] = sW[(CIN + ii) * 64 + tx * 4 + j];
    }
#pragma unroll
    for (int i2 = 0; i2 < 4; ++i2)
#pragma unroll
      for (int j = 0; j < 4; ++j) acc[i2][j] += xa[i2] * wa[j] + ga[i2] * wg[j];
  }
#pragma unroll
  for (int i2 = 0; i2 < 4; ++i2) {
    int b = ty * 4 + i2;
    size_t nb = (size_t)n * 64 + b;
#pragma unroll
    for (int j = 0; j < 4; ++j) {
      int o = tx * 4 + j;
      float hc = tanhf(acc[i2][j] + sB[o]);
      float r = ZR[nb * 128 + 64 + o];
      float hv = h[nb * 64 + o];
      h[nb * 64 + o] = r * hv + (1.0f - r) * hc;
    }
  }
}

// ---------------- output head ------------------------------------------------
__global__ __launch_bounds__(256) void head_kernel(const float* __restrict__ h1,
                                                   const float* __restrict__ cw,
                                                   const float* __restrict__ cb,
                                                   float* __restrict__ out) {
  int i = blockIdx.x * 256 + threadIdx.x;
  if (i >= BB * NN) return;
  int n = i % NN, b = i / NN;
  const float* hrow = h1 + ((size_t)n * 64 + b) * 64;
  float hv[64];
#pragma unroll
  for (int j = 0; j < 64; ++j) hv[j] = hrow[j];
  for (int o = 0; o < 12; ++o) {
    float s = cb[o];
#pragma unroll
    for (int j = 0; j < 64; ++j) s += hv[j] * cw[o * 64 + j];
    out[((size_t)b * 12 + o) * NN + n] = s;
  }
}

__global__ __launch_bounds__(256) void zero_kernel(float* __restrict__ p, int count) {
  int i = blockIdx.x * 256 + threadIdx.x;
  if (i < count) p[i] = 0.0f;
}

extern "C" void kernel_launch(void* const* d_in, const int* in_sizes, int n_in,
                              void* d_out, int out_size, void* d_ws, size_t ws_size,
                              hipStream_t stream) {
  const float* src = (const float*)d_in[0];
  const float* E = (const float*)d_in[1];
  const float* w0g = (const float*)d_in[2];
  const float* b0g = (const float*)d_in[3];
  const float* w0c = (const float*)d_in[4];
  const float* b0c = (const float*)d_in[5];
  const float* w1g = (const float*)d_in[6];
  const float* b1g = (const float*)d_in[7];
  const float* w1c = (const float*)d_in[8];
  const float* b1c = (const float*)d_in[9];
  const float* cw = (const float*)d_in[10];
  const float* cb = (const float*)d_in[11];
  float* out = (float*)d_out;
  float* ws = (float*)d_ws;

  size_t off = 0;
  auto alloc = [&](size_t cnt) {
    float* p = ws + off;
    off += (cnt + 63) & ~(size_t)63;
    return p;
  };
  float* A = alloc((size_t)NN * NN);
  float* XH = alloc((size_t)NN * BB * 128);
  float* G = alloc((size_t)NN * BB * 128);
  float* ZR = alloc((size_t)NN * BB * 128);
  float* h0 = alloc((size_t)NN * BB * 64);
  float* h1 = alloc((size_t)NN * BB * 64);
  if (off * sizeof(float) > ws_size) return;  // ws too small: fail loud (zeros)

  adj_kernel<<<NN, 256, 0, stream>>>(E, A);
  int hcount = 2 * NN * BB * 64;  // h0,h1 contiguous
  zero_kernel<<<(hcount + 255) / 256, 256, 0, stream>>>(h0, hcount);

  const int e0 = NN * BB * 65;
  const int e1 = NN * BB * 128;
  for (int t = 0; t < TT; ++t) {
    // ---- layer 0 (x = source[:,t], Cin = 65) ----
    concat_l0_a<<<(e0 + 255) / 256, 256, 0, stream>>>(src, h0, XH, t);
    gemm_kernel<<<dim3(65, 14), 256, 0, stream>>>(A, XH, G, 64 * 65);
    gate_kernel<65><<<NN, 256, 0, stream>>>(XH, G, E, w0g, b0g, ZR);
    concat_l0_b<<<(e0 + 255) / 256, 256, 0, stream>>>(src, h0, ZR, XH, t);
    gemm_kernel<<<dim3(65, 14), 256, 0, stream>>>(A, XH, G, 64 * 65);
    cand_kernel<65><<<NN, 256, 0, stream>>>(XH, G, E, w0c, b0c, ZR, h0);
    // ---- layer 1 (x = h0 output, Cin = 128) ----
    concat_l1_a<<<(e1 + 255) / 256, 256, 0, stream>>>(h0, h1, XH);
    gemm_kernel<<<dim3(128, 14), 256, 0, stream>>>(A, XH, G, 64 * 128);
    gate_kernel<128><<<NN, 256, 0, stream>>>(XH, G, E, w1g, b1g, ZR);
    concat_l1_b<<<(e1 + 255) / 256, 256, 0, stream>>>(h0, h1, ZR, XH);
    gemm_kernel<<<dim3(128, 14), 256, 0, stream>>>(A, XH, G, 64 * 128);
    cand_kernel<128><<<NN, 256, 0, stream>>>(XH, G, E, w1c, b1c, ZR, h1);
  }
  head_kernel<<<(BB * NN + 255) / 256, 256, 0, stream>>>(h1, cw, cb, out);
}

// Round 3
// 9766.949 us; speedup vs baseline: 2.0853x; 2.0853x over previous
//
#include <hip/hip_runtime.h>
#include <cstddef>

#define NN 883
#define BB 64
#define TT 12
#define EMB 10
#define KPAD 896  // 883 padded up to multiple of 128 (and of 32)

typedef short short8 __attribute__((ext_vector_type(8)));
typedef _Float16 half8 __attribute__((ext_vector_type(8)));
typedef float f32x4 __attribute__((ext_vector_type(4)));

__device__ __forceinline__ void split_f16(float v, _Float16* hp, _Float16* lp) {
  _Float16 h = (_Float16)v;
  *hp = h;
  *lp = (_Float16)(v - (float)h);
}

// -------- adjacency: A = softmax(relu(E E^T), axis=1), emitted as f16 hi/lo --
__global__ __launch_bounds__(256) void adj_kernel(const float* __restrict__ E,
                                                  _Float16* __restrict__ Ah,
                                                  _Float16* __restrict__ Al) {
  const int n = blockIdx.x;
  const int tid = threadIdx.x;
  __shared__ float sE[EMB];
  __shared__ float sred[256];
  if (tid < EMB) sE[tid] = E[n * EMB + tid];
  __syncthreads();
  float d[4];
  float lmax = 0.0f;
#pragma unroll
  for (int q = 0; q < 4; ++q) {
    int m = tid + q * 256;
    d[q] = 0.0f;
    if (m < NN) {
      float s = 0.0f;
#pragma unroll
      for (int e = 0; e < EMB; ++e) s += sE[e] * E[m * EMB + e];
      d[q] = fmaxf(s, 0.0f);
      lmax = fmaxf(lmax, d[q]);
    }
  }
  sred[tid] = lmax;
  __syncthreads();
  for (int s = 128; s > 0; s >>= 1) {
    if (tid < s) sred[tid] = fmaxf(sred[tid], sred[tid + s]);
    __syncthreads();
  }
  const float mx = sred[0];
  __syncthreads();
  float lsum = 0.0f;
#pragma unroll
  for (int q = 0; q < 4; ++q) {
    int m = tid + q * 256;
    if (m < NN) {
      d[q] = expf(d[q] - mx);
      lsum += d[q];
    }
  }
  sred[tid] = lsum;
  __syncthreads();
  for (int s = 128; s > 0; s >>= 1) {
    if (tid < s) sred[tid] += sred[tid + s];
    __syncthreads();
  }
  const float inv = 1.0f / sred[0];
#pragma unroll
  for (int q = 0; q < 4; ++q) {
    int m = tid + q * 256;
    if (m < KPAD) {
      float v = (m < NN) ? d[q] * inv : 0.0f;
      split_f16(v, &Ah[(size_t)n * KPAD + m], &Al[(size_t)n * KPAD + m]);
    }
  }
}

// -------- 3-term split-f16 MFMA GEMM: Y(f32) = (Ah+Al) @ (Xh+Xl), drop Al*Xl -
// 128x128 block tile, 4 waves 2x2, each wave 64x64 via 4x4 MFMA 16x16x32.
__global__ __launch_bounds__(256) void mfma_gemm3(const _Float16* __restrict__ Ah,
                                                  const _Float16* __restrict__ Al,
                                                  const _Float16* __restrict__ Xh,
                                                  const _Float16* __restrict__ Xl,
                                                  float* __restrict__ Y, int L) {
  __shared__ _Float16 sA[2][128][40];    // [hi/lo][m][k], pad 32->40
  __shared__ _Float16 sX[2][4][128][8];  // [hi/lo][k-octet][l][k&7]
  const int tid = threadIdx.x;
  const int lane = tid & 63;
  const int wid = tid >> 6;
  const int wm = (wid >> 1) * 64, wn = (wid & 1) * 64;
  const int bm = blockIdx.y * 128;
  const int bl = blockIdx.x * 128;
  const int l15 = lane & 15, l4 = lane >> 4;

  f32x4 acc[4][4] = {};

  const int xlp = (tid & 63) * 2;  // l-pair this thread stages
  const int xko = tid >> 6;        // k-octet this thread stages

  for (int k0 = 0; k0 < KPAD; k0 += 32) {
    __syncthreads();
    // ---- stage A tiles [128 x 32] hi+lo ----
#pragma unroll
    for (int p = 0; p < 2; ++p) {
      int i = tid + p * 256;
      int m = i >> 2, k8 = (i & 3) * 8;
      *(half8*)&sA[0][m][k8] = *(const half8*)&Ah[(size_t)(bm + m) * KPAD + k0 + k8];
      *(half8*)&sA[1][m][k8] = *(const half8*)&Al[(size_t)(bm + m) * KPAD + k0 + k8];
    }
    // ---- stage X tiles: gather 8 k's per l-pair, transpose into octets ----
    {
      int gl = bl + xlp;
      int kb = k0 + xko * 8;
#pragma unroll
      for (int buf = 0; buf < 2; ++buf) {
        const _Float16* Xp = buf ? Xl : Xh;
        unsigned int v[8];
        if (gl < L) {
#pragma unroll
          for (int j = 0; j < 8; ++j)
            v[j] = *(const unsigned int*)&Xp[(size_t)(kb + j) * L + gl];
        } else {
#pragma unroll
          for (int j = 0; j < 8; ++j) v[j] = 0u;
        }
        short8 lo, hi;
#pragma unroll
        for (int j = 0; j < 8; ++j) {
          lo[j] = (short)(v[j] & 0xFFFFu);
          hi[j] = (short)(v[j] >> 16);
        }
        *(short8*)&sX[buf][xko][xlp][0] = lo;
        *(short8*)&sX[buf][xko][xlp + 1][0] = hi;
      }
    }
    __syncthreads();
    // ---- fragments + 3-term MFMA ----
    half8 afh[4], afl[4], bfh[4], bfl[4];
#pragma unroll
    for (int mi = 0; mi < 4; ++mi) {
      afh[mi] = *(half8*)&sA[0][wm + mi * 16 + l15][l4 * 8];
      afl[mi] = *(half8*)&sA[1][wm + mi * 16 + l15][l4 * 8];
    }
#pragma unroll
    for (int ni = 0; ni < 4; ++ni) {
      bfh[ni] = *(half8*)&sX[0][l4][wn + ni * 16 + l15][0];
      bfl[ni] = *(half8*)&sX[1][l4][wn + ni * 16 + l15][0];
    }
#pragma unroll
    for (int mi = 0; mi < 4; ++mi)
#pragma unroll
      for (int ni = 0; ni < 4; ++ni) {
        acc[mi][ni] = __builtin_amdgcn_mfma_f32_16x16x32_f16(afh[mi], bfh[ni],
                                                             acc[mi][ni], 0, 0, 0);
        acc[mi][ni] = __builtin_amdgcn_mfma_f32_16x16x32_f16(afh[mi], bfl[ni],
                                                             acc[mi][ni], 0, 0, 0);
        acc[mi][ni] = __builtin_amdgcn_mfma_f32_16x16x32_f16(afl[mi], bfh[ni],
                                                             acc[mi][ni], 0, 0, 0);
      }
  }
  // ---- epilogue: D row=(lane>>4)*4+r, col=lane&15 ----
#pragma unroll
  for (int mi = 0; mi < 4; ++mi) {
    int row0 = bm + wm + mi * 16 + l4 * 4;
#pragma unroll
    for (int ni = 0; ni < 4; ++ni) {
      int col = bl + wn + ni * 16 + l15;
      if (col < L) {
#pragma unroll
        for (int r = 0; r < 4; ++r) {
          int row = row0 + r;
          if (row < NN) Y[(size_t)row * L + col] = acc[mi][ni][r];
        }
      }
    }
  }
}

// ---------------- concat builders (node-major [n][b][c], f16 hi/lo out) ------
__global__ __launch_bounds__(256) void concat_l0_a(const float* __restrict__ src,
                                                   const float* __restrict__ h0,
                                                   _Float16* __restrict__ Xh,
                                                   _Float16* __restrict__ Xl, int t) {
  int i = blockIdx.x * 256 + threadIdx.x;
  if (i >= NN * BB * 65) return;
  int c = i % 65;
  int nb = i / 65;
  int b = nb & 63;
  int n = nb >> 6;
  float v = (c == 0) ? src[((size_t)b * TT + t) * NN + n]
                     : h0[(size_t)nb * 64 + (c - 1)];
  split_f16(v, &Xh[i], &Xl[i]);
}

__global__ __launch_bounds__(256) void concat_l0_b(const float* __restrict__ src,
                                                   const float* __restrict__ h0,
                                                   const float* __restrict__ ZR,
                                                   _Float16* __restrict__ Xh,
                                                   _Float16* __restrict__ Xl, int t) {
  int i = blockIdx.x * 256 + threadIdx.x;
  if (i >= NN * BB * 65) return;
  int c = i % 65;
  int nb = i / 65;
  int b = nb & 63;
  int n = nb >> 6;
  float v = (c == 0) ? src[((size_t)b * TT + t) * NN + n]
                     : ZR[(size_t)nb * 128 + (c - 1)] * h0[(size_t)nb * 64 + (c - 1)];
  split_f16(v, &Xh[i], &Xl[i]);
}

__global__ __launch_bounds__(256) void concat_l1_a(const float* __restrict__ h0,
                                                   const float* __restrict__ h1,
                                                   _Float16* __restrict__ Xh,
                                                   _Float16* __restrict__ Xl) {
  int i = blockIdx.x * 256 + threadIdx.x;
  if (i >= NN * BB * 128) return;
  int c = i & 127;
  int nb = i >> 7;
  float v = (c < 64) ? h0[(size_t)nb * 64 + c] : h1[(size_t)nb * 64 + (c - 64)];
  split_f16(v, &Xh[i], &Xl[i]);
}

__global__ __launch_bounds__(256) void concat_l1_b(const float* __restrict__ h0,
                                                   const float* __restrict__ h1,
                                                   const float* __restrict__ ZR,
                                                   _Float16* __restrict__ Xh,
                                                   _Float16* __restrict__ Xl) {
  int i = blockIdx.x * 256 + threadIdx.x;
  if (i >= NN * BB * 128) return;
  int c = i & 127;
  int nb = i >> 7;
  float v = (c < 64) ? h0[(size_t)nb * 64 + c]
                     : ZR[(size_t)nb * 128 + (c - 64)] * h1[(size_t)nb * 64 + (c - 64)];
  split_f16(v, &Xh[i], &Xl[i]);
}

// ---------------- fused node-specific gate gconv + sigmoid -------------------
template <int CIN>
__global__ __launch_bounds__(256) void gate_kernel(const _Float16* __restrict__ Xh,
                                                   const _Float16* __restrict__ Xl,
                                                   const float* __restrict__ G,
                                                   const float* __restrict__ E,
                                                   const float* __restrict__ wpool,
                                                   const float* __restrict__ bpool,
                                                   float* __restrict__ ZR) {
  constexpr int CIN_P = (CIN & 1) ? CIN + 2 : CIN + 3;
  const int n = blockIdx.x;
  const int tid = threadIdx.x;
  __shared__ float sE[EMB];
  __shared__ float sXH[64 * CIN_P];
  __shared__ float sG[64 * CIN_P];
  __shared__ float sW[2 * CIN * 64];
  __shared__ float sB[64];
  if (tid < EMB) sE[tid] = E[n * EMB + tid];
  for (int i = tid; i < 64 * CIN; i += 256) {
    int b = i / CIN, c = i - b * CIN;
    size_t gi = (size_t)n * 64 * CIN + i;
    sXH[b * CIN_P + c] = (float)Xh[gi] + (float)Xl[gi];
    sG[b * CIN_P + c] = G[gi];
  }
  __syncthreads();
  const int tx = tid & 15, ty = tid >> 4;
  for (int och = 0; och < 128; och += 64) {
    for (int i = tid; i < 2 * CIN * 64; i += 256) {
      int ki = i >> 6, oo = i & 63;
      int k = (ki >= CIN) ? 1 : 0;
      int ii = ki - k * CIN;
      float w = 0.0f;
#pragma unroll
      for (int d = 0; d < EMB; ++d)
        w += sE[d] * wpool[(((size_t)d * 2 + k) * CIN + ii) * 128 + och + oo];
      sW[ki * 64 + oo] = w;
    }
    if (tid < 64) {
      float bb = 0.0f;
#pragma unroll
      for (int d = 0; d < EMB; ++d) bb += sE[d] * bpool[d * 128 + och + tid];
      sB[tid] = bb;
    }
    __syncthreads();
    float acc[4][4] = {};
    for (int ii = 0; ii < CIN; ++ii) {
      float xa[4], ga[4], wa[4], wg[4];
#pragma unroll
      for (int i2 = 0; i2 < 4; ++i2) {
        xa[i2] = sXH[(ty * 4 + i2) * CIN_P + ii];
        ga[i2] = sG[(ty * 4 + i2) * CIN_P + ii];
      }
#pragma unroll
      for (int j = 0; j < 4; ++j) {
        wa[j] = sW[ii * 64 + tx * 4 + j];
        wg[j] = sW[(CIN + ii) * 64 + tx * 4 + j];
      }
#pragma unroll
      for (int i2 = 0; i2 < 4; ++i2)
#pragma unroll
        for (int j = 0; j < 4; ++j) acc[i2][j] += xa[i2] * wa[j] + ga[i2] * wg[j];
    }
#pragma unroll
    for (int i2 = 0; i2 < 4; ++i2) {
      int b = ty * 4 + i2;
#pragma unroll
      for (int j = 0; j < 4; ++j) {
        int o = och + tx * 4 + j;
        float v = acc[i2][j] + sB[tx * 4 + j];
        ZR[((size_t)n * 64 + b) * 128 + o] = 1.0f / (1.0f + expf(-v));
      }
    }
    __syncthreads();
  }
}

// ---------------- fused node-specific cand gconv + tanh + GRU update ---------
template <int CIN>
__global__ __launch_bounds__(256) void cand_kernel(const _Float16* __restrict__ Xh,
                                                   const _Float16* __restrict__ Xl,
                                                   const float* __restrict__ G,
                                                   const float* __restrict__ E,
                                                   const float* __restrict__ wpool,
                                                   const float* __restrict__ bpool,
                                                   const float* __restrict__ ZR,
                                                   float* __restrict__ h) {
  constexpr int CIN_P = (CIN & 1) ? CIN + 2 : CIN + 3;
  const int n = blockIdx.x;
  const int tid = threadIdx.x;
  __shared__ float sE[EMB];
  __shared__ float sXH[64 * CIN_P];
  __shared__ float sG[64 * CIN_P];
  __shared__ float sW[2 * CIN * 64];
  __shared__ float sB[64];
  if (tid < EMB) sE[tid] = E[n * EMB + tid];
  for (int i = tid; i < 64 * CIN; i += 256) {
    int b = i / CIN, c = i - b * CIN;
    size_t gi = (size_t)n * 64 * CIN + i;
    sXH[b * CIN_P + c] = (float)Xh[gi] + (float)Xl[gi];
    sG[b * CIN_P + c] = G[gi];
  }
  __syncthreads();
  for (int i = tid; i < 2 * CIN * 64; i += 256) {
    int ki = i >> 6, oo = i & 63;
    int k = (ki >= CIN) ? 1 : 0;
    int ii = ki - k * CIN;
    float w = 0.0f;
#pragma unroll
    for (int d = 0; d < EMB; ++d)
      w += sE[d] * wpool[(((size_t)d * 2 + k) * CIN + ii) * 64 + oo];
    sW[ki * 64 + oo] = w;
  }
  if (tid < 64) {
    float bb = 0.0f;
#pragma unroll
    for (int d = 0; d < EMB; ++d) bb += sE[d] * bpool[d * 64 + tid];
    sB[tid] = bb;
  }
  __syncthreads();
  const int tx = tid & 15, ty = tid >> 4;
  float acc[4][4] = {};
  for (int ii = 0; ii < CIN; ++ii) {
    float xa[4], ga[4], wa[4], wg[4];
#pragma unroll
    for (int i2 = 0; i2 < 4; ++i2) {
      xa[i2] = sXH[(ty * 4 + i2) * CIN_P + ii];
      ga[i2] = sG[(ty * 4 + i2) * CIN_P + ii];
    }
#pragma unroll
    for (int j = 0; j < 4; ++j) {
      wa[j] = sW[ii * 64 + tx * 4 + j];
      wg[j] = sW[(CIN + ii) * 64 + tx * 4 + j];
    }
#pragma unroll
    for (int i2 = 0; i2 < 4; ++i2)
#pragma unroll
      for (int j = 0; j < 4; ++j) acc[i2][j] += xa[i2] * wa[j] + ga[i2] * wg[j];
  }
#pragma unroll
  for (int i2 = 0; i2 < 4; ++i2) {
    int b = ty * 4 + i2;
    size_t nb = (size_t)n * 64 + b;
#pragma unroll
    for (int j = 0; j < 4; ++j) {
      int o = tx * 4 + j;
      float hc = tanhf(acc[i2][j] + sB[o]);
      float r = ZR[nb * 128 + 64 + o];
      float hv = h[nb * 64 + o];
      h[nb * 64 + o] = r * hv + (1.0f - r) * hc;
    }
  }
}

// ---------------- output head ------------------------------------------------
__global__ __launch_bounds__(256) void head_kernel(const float* __restrict__ h1,
                                                   const float* __restrict__ cw,
                                                   const float* __restrict__ cb,
                                                   float* __restrict__ out) {
  int i = blockIdx.x * 256 + threadIdx.x;
  if (i >= BB * NN) return;
  int n = i % NN, b = i / NN;
  const float* hrow = h1 + ((size_t)n * 64 + b) * 64;
  float hv[64];
#pragma unroll
  for (int j = 0; j < 64; ++j) hv[j] = hrow[j];
  for (int o = 0; o < 12; ++o) {
    float s = cb[o];
#pragma unroll
    for (int j = 0; j < 64; ++j) s += hv[j] * cw[o * 64 + j];
    out[((size_t)b * 12 + o) * NN + n] = s;
  }
}

__global__ __launch_bounds__(256) void zero_f32(float* __restrict__ p, int count) {
  int i = blockIdx.x * 256 + threadIdx.x;
  if (i < count) p[i] = 0.0f;
}
__global__ __launch_bounds__(256) void zero_u16(unsigned short* __restrict__ p, int count) {
  int i = blockIdx.x * 256 + threadIdx.x;
  if (i < count) p[i] = 0;
}

extern "C" void kernel_launch(void* const* d_in, const int* in_sizes, int n_in,
                              void* d_out, int out_size, void* d_ws, size_t ws_size,
                              hipStream_t stream) {
  const float* src = (const float*)d_in[0];
  const float* E = (const float*)d_in[1];
  const float* w0g = (const float*)d_in[2];
  const float* b0g = (const float*)d_in[3];
  const float* w0c = (const float*)d_in[4];
  const float* b0c = (const float*)d_in[5];
  const float* w1g = (const float*)d_in[6];
  const float* b1g = (const float*)d_in[7];
  const float* w1c = (const float*)d_in[8];
  const float* b1c = (const float*)d_in[9];
  const float* cw = (const float*)d_in[10];
  const float* cb = (const float*)d_in[11];
  float* out = (float*)d_out;
  float* ws = (float*)d_ws;

  size_t off = 0;
  auto alloc = [&](size_t cnt) {  // cnt in floats
    float* p = ws + off;
    off += (cnt + 63) & ~(size_t)63;
    return p;
  };
  const int L0 = 64 * 65;   // 4160
  const int L1 = 64 * 128;  // 8192
  _Float16* Ah = (_Float16*)alloc((size_t)KPAD * KPAD / 2);
  _Float16* Al = (_Float16*)alloc((size_t)KPAD * KPAD / 2);
  _Float16* X0h = (_Float16*)alloc((size_t)KPAD * L0 / 2);
  _Float16* X0l = (_Float16*)alloc((size_t)KPAD * L0 / 2);
  _Float16* X1h = (_Float16*)alloc((size_t)KPAD * L1 / 2);
  _Float16* X1l = (_Float16*)alloc((size_t)KPAD * L1 / 2);
  float* G = alloc((size_t)NN * L1);
  float* ZR = alloc((size_t)NN * BB * 128);
  float* h0 = alloc((size_t)NN * BB * 64);
  float* h1 = alloc((size_t)NN * BB * 64);
  if (off * sizeof(float) > ws_size) return;  // ws too small: fail loud (zeros)

  adj_kernel<<<NN, 256, 0, stream>>>(E, Ah, Al);
  int hcount = 2 * NN * BB * 64;  // h0,h1 contiguous
  zero_f32<<<(hcount + 255) / 256, 256, 0, stream>>>(h0, hcount);
  // zero X staging buffers (pad rows must be 0; real rows overwritten per step)
  zero_u16<<<(2 * KPAD * L0 + 255) / 256, 256, 0, stream>>>((unsigned short*)X0h,
                                                            2 * KPAD * L0);
  zero_u16<<<(2 * KPAD * L1 + 255) / 256, 256, 0, stream>>>((unsigned short*)X1h,
                                                            2 * KPAD * L1);

  const int e0 = NN * BB * 65;
  const int e1 = NN * BB * 128;
  const int gx0 = (L0 + 127) / 128;  // 33
  const int gx1 = L1 / 128;          // 64
  for (int t = 0; t < TT; ++t) {
    // ---- layer 0 (x = source[:,t], Cin = 65) ----
    concat_l0_a<<<(e0 + 255) / 256, 256, 0, stream>>>(src, h0, X0h, X0l, t);
    mfma_gemm3<<<dim3(gx0, 7), 256, 0, stream>>>(Ah, Al, X0h, X0l, G, L0);
    gate_kernel<65><<<NN, 256, 0, stream>>>(X0h, X0l, G, E, w0g, b0g, ZR);
    concat_l0_b<<<(e0 + 255) / 256, 256, 0, stream>>>(src, h0, ZR, X0h, X0l, t);
    mfma_gemm3<<<dim3(gx0, 7), 256, 0, stream>>>(Ah, Al, X0h, X0l, G, L0);
    cand_kernel<65><<<NN, 256, 0, stream>>>(X0h, X0l, G, E, w0c, b0c, ZR, h0);
    // ---- layer 1 (x = h0 output, Cin = 128) ----
    concat_l1_a<<<(e1 + 255) / 256, 256, 0, stream>>>(h0, h1, X1h, X1l);
    mfma_gemm3<<<dim3(gx1, 7), 256, 0, stream>>>(Ah, Al, X1h, X1l, G, L1);
    gate_kernel<128><<<NN, 256, 0, stream>>>(X1h, X1l, G, E, w1g, b1g, ZR);
    concat_l1_b<<<(e1 + 255) / 256, 256, 0, stream>>>(h0, h1, ZR, X1h, X1l);
    mfma_gemm3<<<dim3(gx1, 7), 256, 0, stream>>>(Ah, Al, X1h, X1l, G, L1);
    cand_kernel<128><<<NN, 256, 0, stream>>>(X1h, X1l, G, E, w1c, b1c, ZR, h1);
  }
  head_kernel<<<(BB * NN + 255) / 256, 256, 0, stream>>>(h1, cw, cb, out);
}